// Round 6
// baseline (55.457 us; speedup 1.0000x reference)
//
#include <hip/hip_runtime.h>
#include <math.h>
#include <stdint.h>

// Problem constants: B=8, S=4096, D=1024, Q=16 -> 32768 rows
#define ROWS_TOTAL 32768
#define DDIM 1024
#define QDIM 16

typedef __attribute__((ext_vector_type(8))) short bf16x8;  // 8 bf16 (4 VGPRs)
typedef __attribute__((ext_vector_type(4))) float f32x4;   // 4 f32 acc

union ABfrag { uint32_t u[4]; bf16x8 v; };

// pack the high 16 bits (truncated bf16) of two f32 bit patterns:
// result low ushort = a.hi16 (lower-k element), high ushort = b.hi16
__device__ __forceinline__ uint32_t packhi(uint32_t a, uint32_t b) {
  return __builtin_amdgcn_perm(b, a, 0x07060302u);
}

// ============================================================
// Kernel Z (MFMA, split-K): z[row][q] = cos(relu(x[row]@W1+b1)+theta)
//
// Block = 512 threads = 8 waves, ONE 16-row tile per block (2048 blocks).
// Wave w owns k-slice [128w, 128w+128) = 4 MFMA steps of K=32.
//   - W1 fragments for the slice live in REGISTERS (32 scalar L2-hot
//     loads -> split-bf16 -> 32 VGPR). No 64KB W1 LDS anymore.
//   - All 8 x-loads (dwordx4) issued UPFRONT, consumed in issue order:
//     no rotating buffer for the compiler to de-pipeline; counted vmcnt
//     falls out naturally. Same per-instruction global pattern as r5
//     (isolates the TLP/pipelining variable).
//   - Split-bf16 accuracy: acc += Ahi*Bhi + Alo*Bhi + Ahi*Blo.
//   - Partial sums combined via 8KB LDS + one barrier; wave 0 applies
//     bias/relu/theta/cos and stores the 1KB z tile.
// LDS 8KB, target VGPR <=128 -> 4 waves/SIMD = 16 waves/CU (2x round 5).
// Fragment maps (verified by rounds 4/5 passing, random data):
//   A: lane l -> row l&15, k-slots kb+32s+4g+{0..3} U kb+32s+16+4g+{0..3}
//   B: lane l -> col l&15, same k-permutation (common perm = invariant)
//   C: lane l -> D[(l>>4)*4+i][l&15]
// ============================================================
#define ZTPB 512
#define ZWPB 8
#define ZNBLOCKS (ROWS_TOTAL / 16)   // 2048

__global__ __launch_bounds__(ZTPB, 4)
void z_kernel(const float* __restrict__ x, const float* __restrict__ W1,
              const float* __restrict__ b1, const float* __restrict__ theta,
              float* __restrict__ z, int zstride) {
  const int t    = threadIdx.x;
  const int lane = t & 63;
  const int wid  = t >> 6;     // k-slice owner, 0..7
  const int g    = lane >> 4;  // lane-group
  const int q5   = lane & 15;

  __shared__ __align__(16) float red[ZWPB][64][4];  // 8 KB partial buffer

  const int row0 = blockIdx.x * 16;
  const int kb   = wid * 128;  // this wave's k-base

  // epilogue constants (hoisted so the loads' latency is hidden)
  const float bq = b1[q5];
  const float tq = theta[q5];

  // ---- W1 slice: 32 scalar loads (64KB total, L2-hot across blocks)
  // wf[s][j] = W1[kb + 32s + perm(g,j)][q5], perm j<4 -> 4g+j, else 16+4g+j-4
  float wf[4][8];
#pragma unroll
  for (int s = 0; s < 4; ++s) {
    const float* wp = W1 + (size_t)(kb + 32 * s + 4 * g) * QDIM + q5;
#pragma unroll
    for (int j = 0; j < 4; ++j) wf[s][j] = wp[(size_t)j * QDIM];
#pragma unroll
    for (int j = 0; j < 4; ++j) wf[s][4 + j] = wp[(size_t)(16 + j) * QDIM];
  }

  // ---- x: all 4 steps' loads issued upfront (8 dwordx4, HBM)
  const float* xl = x + (size_t)(row0 + q5) * DDIM + kb + 4 * g;
  float4 a0[4], a1[4];
#pragma unroll
  for (int s = 0; s < 4; ++s) {
    a0[s] = *reinterpret_cast<const float4*>(xl + 32 * s);
    a1[s] = *reinterpret_cast<const float4*>(xl + 32 * s + 16);
  }

  // ---- convert W1 to split-bf16 B-fragments (waits W1 loads only;
  //      the 8 x loads stay outstanding under counted vmcnt)
  ABfrag bhi[4], blo[4];
#pragma unroll
  for (int s = 0; s < 4; ++s) {
    uint32_t u[8], lo[8];
#pragma unroll
    for (int j = 0; j < 8; ++j) {
      u[j]  = __float_as_uint(wf[s][j]);
      lo[j] = __float_as_uint(wf[s][j] - __uint_as_float(u[j] & 0xFFFF0000u));
    }
    bhi[s].u[0] = packhi(u[0], u[1]);   bhi[s].u[1] = packhi(u[2], u[3]);
    bhi[s].u[2] = packhi(u[4], u[5]);   bhi[s].u[3] = packhi(u[6], u[7]);
    blo[s].u[0] = packhi(lo[0], lo[1]); blo[s].u[1] = packhi(lo[2], lo[3]);
    blo[s].u[2] = packhi(lo[4], lo[5]); blo[s].u[3] = packhi(lo[6], lo[7]);
  }

  // ---- 4 MFMA steps over this wave's k-slice
  f32x4 acc = {0.f, 0.f, 0.f, 0.f};
#pragma unroll
  for (int s = 0; s < 4; ++s) {
    const float fv[8] = {a0[s].x, a0[s].y, a0[s].z, a0[s].w,
                         a1[s].x, a1[s].y, a1[s].z, a1[s].w};
    uint32_t u[8], lo[8];
#pragma unroll
    for (int j = 0; j < 8; ++j) {
      u[j]  = __float_as_uint(fv[j]);
      lo[j] = __float_as_uint(fv[j] - __uint_as_float(u[j] & 0xFFFF0000u));
    }
    ABfrag ahi, alo;
    ahi.u[0] = packhi(u[0], u[1]);   ahi.u[1] = packhi(u[2], u[3]);
    ahi.u[2] = packhi(u[4], u[5]);   ahi.u[3] = packhi(u[6], u[7]);
    alo.u[0] = packhi(lo[0], lo[1]); alo.u[1] = packhi(lo[2], lo[3]);
    alo.u[2] = packhi(lo[4], lo[5]); alo.u[3] = packhi(lo[6], lo[7]);

    acc = __builtin_amdgcn_mfma_f32_16x16x32_bf16(ahi.v, bhi[s].v, acc, 0, 0, 0);
    acc = __builtin_amdgcn_mfma_f32_16x16x32_bf16(alo.v, bhi[s].v, acc, 0, 0, 0);
    acc = __builtin_amdgcn_mfma_f32_16x16x32_bf16(ahi.v, blo[s].v, acc, 0, 0, 0);
  }

  // ---- combine split-K partials (lane-linear 16B: conflict-free)
  *reinterpret_cast<f32x4*>(&red[wid][lane][0]) = acc;
  __syncthreads();

  if (wid == 0) {
    f32x4 s0 = *reinterpret_cast<const f32x4*>(&red[0][lane][0]);
#pragma unroll
    for (int w = 1; w < ZWPB; ++w)
      s0 += *reinterpret_cast<const f32x4*>(&red[w][lane][0]);

    const int r0 = g * 4;
#pragma unroll
    for (int i = 0; i < 4; ++i) {
      const float sv = fmaxf(s0[i] + bq, 0.f) + tq;
      z[(size_t)(row0 + r0 + i) * zstride + q5] = __cosf(sv);
    }
  }
}

// ============================================================
// Kernel O: out[row] = z[row] @ W2 + b2  (unchanged; ~5 us, L3-absorbed)
//   z/out intentionally NOT __restrict__ (aliased fallback).
// ============================================================
#define OTPB 256
#define ORPB 16
#define ONBLOCKS (ROWS_TOTAL / ORPB)  // 2048

__global__ __launch_bounds__(OTPB, 4)
void o_kernel(const float* z, int zstride, const float* __restrict__ W2,
              const float* __restrict__ b2, float* out) {
  const int t   = threadIdx.x;
  const int col = 4 * t;

  float4 w2r[QDIM];
#pragma unroll
  for (int q = 0; q < QDIM; ++q)
    w2r[q] = *reinterpret_cast<const float4*>(W2 + (size_t)q * DDIM + col);
  const float4 bb = *reinterpret_cast<const float4*>(b2 + col);

  const int row0 = blockIdx.x * ORPB;

  const float* zp0 = z + (size_t)row0 * zstride;
  float4 zc0 = *reinterpret_cast<const float4*>(zp0 + 0);
  float4 zc1 = *reinterpret_cast<const float4*>(zp0 + 4);
  float4 zc2 = *reinterpret_cast<const float4*>(zp0 + 8);
  float4 zc3 = *reinterpret_cast<const float4*>(zp0 + 12);

#pragma unroll
  for (int r = 0; r < ORPB; ++r) {
    float4 zn0 = zc0, zn1 = zc1, zn2 = zc2, zn3 = zc3;
    if (r + 1 < ORPB) {
      const float* znp = z + (size_t)(row0 + r + 1) * zstride;
      zn0 = *reinterpret_cast<const float4*>(znp + 0);
      zn1 = *reinterpret_cast<const float4*>(znp + 4);
      zn2 = *reinterpret_cast<const float4*>(znp + 8);
      zn3 = *reinterpret_cast<const float4*>(znp + 12);
    }

    const float zv[16] = {zc0.x, zc0.y, zc0.z, zc0.w,
                          zc1.x, zc1.y, zc1.z, zc1.w,
                          zc2.x, zc2.y, zc2.z, zc2.w,
                          zc3.x, zc3.y, zc3.z, zc3.w};
    float4 acc = bb;
#pragma unroll
    for (int q = 0; q < QDIM; ++q) {
      acc.x = fmaf(zv[q], w2r[q].x, acc.x);
      acc.y = fmaf(zv[q], w2r[q].y, acc.y);
      acc.z = fmaf(zv[q], w2r[q].z, acc.z);
      acc.w = fmaf(zv[q], w2r[q].w, acc.w);
    }
    *reinterpret_cast<float4*>(out + (size_t)(row0 + r) * DDIM + col) = acc;

    zc0 = zn0; zc1 = zn1; zc2 = zn2; zc3 = zn3;
  }
}

extern "C" void kernel_launch(void* const* d_in, const int* in_sizes, int n_in,
                              void* d_out, int out_size, void* d_ws, size_t ws_size,
                              hipStream_t stream) {
  const float* x     = (const float*)d_in[0];
  const float* W1    = (const float*)d_in[1];
  const float* b1    = (const float*)d_in[2];
  const float* theta = (const float*)d_in[3];
  const float* W2    = (const float*)d_in[4];
  const float* b2    = (const float*)d_in[5];
  float* out = (float*)d_out;

  const size_t zbytes = (size_t)ROWS_TOTAL * QDIM * sizeof(float);  // 2 MB
  float* zbuf;
  int zstride;
  if (d_ws != nullptr && ws_size >= zbytes) {
    zbuf = (float*)d_ws;  // compact z in workspace
    zstride = QDIM;
  } else {
    zbuf = out;           // fallback: stash z in out[row][0:16]
    zstride = DDIM;
  }

  z_kernel<<<dim3(ZNBLOCKS), dim3(ZTPB), 0, stream>>>(x, W1, b1, theta, zbuf, zstride);
  o_kernel<<<dim3(ONBLOCKS), dim3(OTPB), 0, stream>>>(zbuf, zstride, W2, b2, out);
}

// Round 7
// 52.773 us; speedup vs baseline: 1.0509x; 1.0509x over previous
//
#include <hip/hip_runtime.h>
#include <math.h>
#include <stdint.h>

// Problem constants: B=8, S=4096, D=1024, Q=16 -> 32768 rows
#define ROWS_TOTAL 32768
#define DDIM 1024
#define QDIM 16

typedef __attribute__((ext_vector_type(8))) short bf16x8;  // 8 bf16 (4 VGPRs)
typedef __attribute__((ext_vector_type(4))) float f32x4;   // 4 f32 acc

union ABfrag { uint32_t u[4]; bf16x8 v; };

// pack the high 16 bits (truncated bf16) of two f32 bit patterns:
// result low ushort = a.hi16 (lower-k element), high ushort = b.hi16
__device__ __forceinline__ uint32_t packhi(uint32_t a, uint32_t b) {
  return __builtin_amdgcn_perm(b, a, 0x07060302u);
}

// ============================================================
// Kernel Z (MFMA, split-K, LINEAR-STAGED x): round 6 structure with ONE
// change: x goes global->LDS->fragments instead of strided per-lane
// global loads.
//   - Staging: wave w loads rows 2w,2w+1 of the block's 16-row tile as
//     4x1KB FULLY CONTIGUOUS dwordx4 instructions per row (DRAM sees
//     sequential bursts, all channels swept uniformly), then
//     ds_write_b128 at 16B-unit position u ^ (r&7)  (XOR swizzle).
//   - Fragments: after one barrier, lane l ds_read_b128's row (l&15),
//     units (32w + 8s + g) ^ (r&7): swizzle balances the 16-row read
//     across all 8 bank-sets (8 lanes/set = minimum cycles).
//   - Everything else IDENTICAL to round 6: W1 slice in registers
//     (L2-hot scalar loads), split-bf16 (acc += Ahi*Bhi+Alo*Bhi+Ahi*Blo),
//     4 MFMA steps/wave, 8KB LDS split-K reduce, wave0 epilogue.
// LDS 64KB(xs) + 8KB(red) = 72KB -> 2 blocks/CU = 16 waves/CU (same TLP
// as round 6 -> the global access pattern is the ONLY changed variable).
// ============================================================
#define ZTPB 512
#define ZWPB 8
#define ZNBLOCKS (ROWS_TOTAL / 16)   // 2048

__global__ __launch_bounds__(ZTPB, 4)
void z_kernel(const float* __restrict__ x, const float* __restrict__ W1,
              const float* __restrict__ b1, const float* __restrict__ theta,
              float* __restrict__ z, int zstride) {
  const int t    = threadIdx.x;
  const int lane = t & 63;
  const int wid  = t >> 6;     // k-slice owner, 0..7
  const int g    = lane >> 4;  // lane-group
  const int q5   = lane & 15;

  __shared__ __align__(16) float xs[16][DDIM];      // 64 KB, swizzled 16B units
  __shared__ __align__(16) float red[ZWPB][64][4];  // 8 KB partial buffer

  const int row0 = blockIdx.x * 16;
  const int kb   = wid * 128;  // this wave's k-base (floats)

  // epilogue constants (hoisted; latency hidden under everything else)
  const float bq = b1[q5];
  const float tq = theta[q5];

  // ---- W1 slice: 32 scalar loads (64KB total, L2-hot across blocks)
  // wf[s][j] = W1[kb + 32s + perm(g,j)][q5], perm j<4 -> 4g+j, else 16+4g+j-4
  float wf[4][8];
#pragma unroll
  for (int s = 0; s < 4; ++s) {
    const float* wp = W1 + (size_t)(kb + 32 * s + 4 * g) * QDIM + q5;
#pragma unroll
    for (int j = 0; j < 4; ++j) wf[s][j] = wp[(size_t)j * QDIM];
#pragma unroll
    for (int j = 0; j < 4; ++j) wf[s][4 + j] = wp[(size_t)(16 + j) * QDIM];
  }

  // ---- stage x: wave w owns rows 2w, 2w+1. 8 contiguous-1KB loads,
  //      then 8 swizzled ds_write_b128 (consumed in issue order).
  float4 st[8];
  {
    const int rs = 2 * wid;
#pragma unroll
    for (int rr = 0; rr < 2; ++rr) {
      const float* xp = x + (size_t)(row0 + rs + rr) * DDIM;
#pragma unroll
      for (int p = 0; p < 4; ++p)
        st[rr * 4 + p] =
            *reinterpret_cast<const float4*>(xp + 4 * (64 * p + lane));
    }
#pragma unroll
    for (int rr = 0; rr < 2; ++rr) {
      const int r = rs + rr;
#pragma unroll
      for (int p = 0; p < 4; ++p) {
        const int u = 64 * p + lane;           // 16B unit within the row
        *reinterpret_cast<float4*>(&xs[r][4 * (u ^ (r & 7))]) =
            st[rr * 4 + p];
      }
    }
  }

  // ---- convert W1 to split-bf16 B-fragments (overlaps other waves' staging)
  ABfrag bhi[4], blo[4];
#pragma unroll
  for (int s = 0; s < 4; ++s) {
    uint32_t u[8], lo[8];
#pragma unroll
    for (int j = 0; j < 8; ++j) {
      u[j]  = __float_as_uint(wf[s][j]);
      lo[j] = __float_as_uint(wf[s][j] - __uint_as_float(u[j] & 0xFFFF0000u));
    }
    bhi[s].u[0] = packhi(u[0], u[1]);   bhi[s].u[1] = packhi(u[2], u[3]);
    bhi[s].u[2] = packhi(u[4], u[5]);   bhi[s].u[3] = packhi(u[6], u[7]);
    blo[s].u[0] = packhi(lo[0], lo[1]); blo[s].u[1] = packhi(lo[2], lo[3]);
    blo[s].u[2] = packhi(lo[4], lo[5]); blo[s].u[3] = packhi(lo[6], lo[7]);
  }

  __syncthreads();  // xs tile visible

  // ---- fragments from LDS: row (lane&15), k-slice units (32wid + 8s + g)
  const int rr = lane & 15;
  const int ub = 32 * wid;
  float4 a0[4], a1[4];
#pragma unroll
  for (int s = 0; s < 4; ++s) {
    a0[s] = *reinterpret_cast<const float4*>(
        &xs[rr][4 * ((ub + 8 * s + g) ^ (rr & 7))]);
    a1[s] = *reinterpret_cast<const float4*>(
        &xs[rr][4 * ((ub + 8 * s + 4 + g) ^ (rr & 7))]);
  }

  // ---- 4 MFMA steps over this wave's k-slice
  f32x4 acc = {0.f, 0.f, 0.f, 0.f};
#pragma unroll
  for (int s = 0; s < 4; ++s) {
    const float fv[8] = {a0[s].x, a0[s].y, a0[s].z, a0[s].w,
                         a1[s].x, a1[s].y, a1[s].z, a1[s].w};
    uint32_t u[8], lo[8];
#pragma unroll
    for (int j = 0; j < 8; ++j) {
      u[j]  = __float_as_uint(fv[j]);
      lo[j] = __float_as_uint(fv[j] - __uint_as_float(u[j] & 0xFFFF0000u));
    }
    ABfrag ahi, alo;
    ahi.u[0] = packhi(u[0], u[1]);   ahi.u[1] = packhi(u[2], u[3]);
    ahi.u[2] = packhi(u[4], u[5]);   ahi.u[3] = packhi(u[6], u[7]);
    alo.u[0] = packhi(lo[0], lo[1]); alo.u[1] = packhi(lo[2], lo[3]);
    alo.u[2] = packhi(lo[4], lo[5]); alo.u[3] = packhi(lo[6], lo[7]);

    acc = __builtin_amdgcn_mfma_f32_16x16x32_bf16(ahi.v, bhi[s].v, acc, 0, 0, 0);
    acc = __builtin_amdgcn_mfma_f32_16x16x32_bf16(alo.v, bhi[s].v, acc, 0, 0, 0);
    acc = __builtin_amdgcn_mfma_f32_16x16x32_bf16(ahi.v, blo[s].v, acc, 0, 0, 0);
  }

  // ---- combine split-K partials (lane-linear 16B: conflict-free)
  *reinterpret_cast<f32x4*>(&red[wid][lane][0]) = acc;
  __syncthreads();

  if (wid == 0) {
    f32x4 s0 = *reinterpret_cast<const f32x4*>(&red[0][lane][0]);
#pragma unroll
    for (int w = 1; w < ZWPB; ++w)
      s0 += *reinterpret_cast<const f32x4*>(&red[w][lane][0]);

    const int r0 = g * 4;
#pragma unroll
    for (int i = 0; i < 4; ++i) {
      const float sv = fmaxf(s0[i] + bq, 0.f) + tq;
      z[(size_t)(row0 + r0 + i) * zstride + q5] = __cosf(sv);
    }
  }
}

// ============================================================
// Kernel O: out[row] = z[row] @ W2 + b2  (unchanged; ~5 us, L3-absorbed)
//   z/out intentionally NOT __restrict__ (aliased fallback).
// ============================================================
#define OTPB 256
#define ORPB 16
#define ONBLOCKS (ROWS_TOTAL / ORPB)  // 2048

__global__ __launch_bounds__(OTPB, 4)
void o_kernel(const float* z, int zstride, const float* __restrict__ W2,
              const float* __restrict__ b2, float* out) {
  const int t   = threadIdx.x;
  const int col = 4 * t;

  float4 w2r[QDIM];
#pragma unroll
  for (int q = 0; q < QDIM; ++q)
    w2r[q] = *reinterpret_cast<const float4*>(W2 + (size_t)q * DDIM + col);
  const float4 bb = *reinterpret_cast<const float4*>(b2 + col);

  const int row0 = blockIdx.x * ORPB;

  const float* zp0 = z + (size_t)row0 * zstride;
  float4 zc0 = *reinterpret_cast<const float4*>(zp0 + 0);
  float4 zc1 = *reinterpret_cast<const float4*>(zp0 + 4);
  float4 zc2 = *reinterpret_cast<const float4*>(zp0 + 8);
  float4 zc3 = *reinterpret_cast<const float4*>(zp0 + 12);

#pragma unroll
  for (int r = 0; r < ORPB; ++r) {
    float4 zn0 = zc0, zn1 = zc1, zn2 = zc2, zn3 = zc3;
    if (r + 1 < ORPB) {
      const float* znp = z + (size_t)(row0 + r + 1) * zstride;
      zn0 = *reinterpret_cast<const float4*>(znp + 0);
      zn1 = *reinterpret_cast<const float4*>(znp + 4);
      zn2 = *reinterpret_cast<const float4*>(znp + 8);
      zn3 = *reinterpret_cast<const float4*>(znp + 12);
    }

    const float zv[16] = {zc0.x, zc0.y, zc0.z, zc0.w,
                          zc1.x, zc1.y, zc1.z, zc1.w,
                          zc2.x, zc2.y, zc2.z, zc2.w,
                          zc3.x, zc3.y, zc3.z, zc3.w};
    float4 acc = bb;
#pragma unroll
    for (int q = 0; q < QDIM; ++q) {
      acc.x = fmaf(zv[q], w2r[q].x, acc.x);
      acc.y = fmaf(zv[q], w2r[q].y, acc.y);
      acc.z = fmaf(zv[q], w2r[q].z, acc.z);
      acc.w = fmaf(zv[q], w2r[q].w, acc.w);
    }
    *reinterpret_cast<float4*>(out + (size_t)(row0 + r) * DDIM + col) = acc;

    zc0 = zn0; zc1 = zn1; zc2 = zn2; zc3 = zn3;
  }
}

extern "C" void kernel_launch(void* const* d_in, const int* in_sizes, int n_in,
                              void* d_out, int out_size, void* d_ws, size_t ws_size,
                              hipStream_t stream) {
  const float* x     = (const float*)d_in[0];
  const float* W1    = (const float*)d_in[1];
  const float* b1    = (const float*)d_in[2];
  const float* theta = (const float*)d_in[3];
  const float* W2    = (const float*)d_in[4];
  const float* b2    = (const float*)d_in[5];
  float* out = (float*)d_out;

  const size_t zbytes = (size_t)ROWS_TOTAL * QDIM * sizeof(float);  // 2 MB
  float* zbuf;
  int zstride;
  if (d_ws != nullptr && ws_size >= zbytes) {
    zbuf = (float*)d_ws;  // compact z in workspace
    zstride = QDIM;
  } else {
    zbuf = out;           // fallback: stash z in out[row][0:16]
    zstride = DDIM;
  }

  z_kernel<<<dim3(ZNBLOCKS), dim3(ZTPB), 0, stream>>>(x, W1, b1, theta, zbuf, zstride);
  o_kernel<<<dim3(ONBLOCKS), dim3(OTPB), 0, stream>>>(zbuf, zstride, W2, b2, out);
}